// Round 15
// baseline (57.488 us; speedup 1.0000x reference)
//
#include <hip/hip_runtime.h>
#include <math.h>
#include <utility>

// EPG simulation, one thread per pixel. OCCUPANCY PROBE: lean in-place core
// (R5-proven arithmetic, minimal temps ~80 live VGPRs) + R4-proven reg-ring
// float4 epilogue, under __launch_bounds__(256, 6).
// R13 measured: hipcc launch_bounds arg2 = CUDA-style min BLOCKS/CU.
//   (256,6) -> VGPR cap 131072/(6*256) = 85 -> 24 waves/CU = 6 waves/SIMD
//   (vs all prior rounds' 4 waves/SIMD at ~110-120 VGPR).
// Theory: T = instrs x eff_cyc(occ); measured eff 4.9 cyc at 4 waves/SIMD vs
// m07's 3.05 at 8 waves/SIMD -> more waves is the only unexplored eff lever.
//
// State invariant: F+ = i*fp, F- = i*fm (pure imaginary), Z real.
// Band A(t) = min(t, 17, 31-t) <= 15 (forward: k<=t populated; backward:
// slot k at step t influences echoes >= t+k only). fm[15]==0 invariant.
// In-place rolling update (j = A down to 0, rm_prev carries Rm[j+1]):
//   rp,rm,zn from (fp,fm,z)[j]; fp[j+1]=rp (j<=14), fm[j]=rm_prev, z[j]=zn
//   then fp[0]=fm[0] (S[0:2,4]=1 quirk -> both get Rm[1]), z[0]+=inj.
// Rm[0] skipped (never used). Echo = |c2*fp0 + s2*fm0 - sa*z0| (PD folded
// into state; never divide by E2 — it underflows, R12).

#define NPULSES 32
#define NSLOT 16

__host__ __device__ constexpr int cmin3(int a, int b, int c) {
    int m = a < b ? a : b; return m < c ? m : c;
}

template <typename F, int... Ts>
__device__ __forceinline__ void static_for(F&& f, std::integer_sequence<int, Ts...>) {
    (f(std::integral_constant<int, Ts>{}), ...);
}

__global__ __launch_bounds__(256, 6) void epg_kernel(
    const float* __restrict__ qm,   // (3, npix) flattened
    const int* __restrict__ tr_ptr, // scalar TR
    float* __restrict__ out,        // (npix, 32)
    int npix)
{
    const int p = blockIdx.x * 256 + threadIdx.x;
    if (p >= npix) return;

    float PD = qm[p];
    float T1 = fmaf(qm[npix + p], 5000.0f, 0.01f);
    float T2 = fmaf(qm[2 * npix + p], 1500.0f, 0.01f);
    float TR = (float)(*tr_ptr);
    float E1 = __expf(-TR / T1);
    float E2 = __expf(-TR / T2);

    // RF rotation constants, alpha = pi/4, phi = 0
    const float c2 = 0.8535533905932737f;   // cos^2(pi/8)
    const float s2 = 0.1464466094067263f;   // sin^2(pi/8)
    const float sa = 0.7071067811865476f;   // sin(pi/4) == cos(pi/4)

    float Aa = -E2 * c2;
    float Bb = -E2 * s2;
    float Cc =  E2 * sa;
    float Dd =  E1 * 0.5f * sa;
    float Ez =  E1 * sa;                    // E1*cos(alpha), ca == sa
    float inj = (1.0f - E1) * PD;           // PD folded into state scale

    float fp[NSLOT], fm[NSLOT], z[NSLOT];
    #pragma unroll
    for (int k = 0; k < NSLOT; ++k) { fp[k] = 0.0f; fm[k] = 0.0f; z[k] = 0.0f; }
    z[0] = PD;

    float4* o4 = (float4*)(out + (size_t)p * NPULSES);
    float ebuf[4];

    static_for([&](auto tc) {
        constexpr int t = decltype(tc)::value;

        // echo: unscaled rotated F+_0 magnitude (E2/conj not folded in)
        float e = fmaf(c2, fp[0], fmaf(s2, fm[0], -sa * z[0]));
        ebuf[t & 3] = fabsf(e);
        if constexpr ((t & 3) == 3)
            o4[t >> 2] = make_float4(ebuf[0], ebuf[1], ebuf[2], ebuf[3]);

        if constexpr (t < NPULSES - 1) {
            constexpr int A = cmin3(t, NSLOT - 1, (NPULSES - 1) - t);  // <= 15
            float rm_prev = 0.0f;    // Rm[A+1]: exact 0 (growing) or dead (shrinking)
            static_for([&](auto jc) {
                constexpr int j = A - decltype(jc)::value;   // A down to 0
                float pk = fp[j], zk = z[j];
                float Cz = Cc * zk;
                if constexpr (j == NSLOT - 1) {
                    // fm[15]==0 invariant; fp[16] dead -> no rp
                    float rm = fmaf(Bb, pk, -Cz);
                    z[j]  = fmaf(Ez, zk, Dd * pk);
                    fm[j] = rm_prev;                 // = 0, preserves invariant
                    rm_prev = rm;
                } else {
                    float mk = fm[j];
                    float rp = fmaf(Aa, pk, fmaf(Bb, mk, Cz));
                    float zn = fmaf(Ez, zk, Dd * (pk - mk));
                    if constexpr (j > 0) {
                        float rm = fmaf(Bb, pk, fmaf(Aa, mk, -Cz));
                        fp[j + 1] = rp; fm[j] = rm_prev; z[j] = zn;
                        rm_prev = rm;
                    } else {
                        // Rm[0] never used by the shift
                        fp[1] = rp; fm[0] = rm_prev; z[0] = zn;
                    }
                }
            }, std::make_integer_sequence<int, A + 1>{});
            fp[0] = fm[0];   // quirk: F+_0 and F-_0 both get Rm[1]
            z[0] += inj;
        }
    }, std::make_integer_sequence<int, NPULSES>{});
}

extern "C" void kernel_launch(void* const* d_in, const int* in_sizes, int n_in,
                              void* d_out, int out_size, void* d_ws, size_t ws_size,
                              hipStream_t stream) {
    const float* qm = (const float*)d_in[0];
    const int* tr = (const int*)d_in[2];   // d_in[1] = n_pulses (compile-time 32)
    float* out = (float*)d_out;
    int npix = in_sizes[0] / 3;

    int block = 256;
    int grid = (npix + block - 1) / block;
    epg_kernel<<<grid, block, 0, stream>>>(qm, tr, out, npix);
}